// Round 1
// baseline (4158.989 us; speedup 1.0000x reference)
//
#include <hip/hip_runtime.h>
#include <hip/hip_bf16.h>

// GRU-scan model, MI355X. Strategy:
//  k1_prep : cvt weights to bf16, fold biases, init h/acc buffers (in ws)
//  k2_xi   : xi[t][b][3H] = x@W_ih^T + (b_ih + b_hh_{r,z} fold)   (bf16, tiled MFMA)
//  k2_tio  : tio[t][b][O] = silu(x@Wt^T + bt)@Wo^T + bo           (bf16, fused 2-stage)
//  k3_rec  : persistent recurrence v2: 256 blocks x 512 thr (8 waves = 2/SIMD),
//            ONE barrier/step, h double-buffered in LDS, wave-local gate
//            redistribution, pending (pipelined) proj/gate combine.
//  k4_out  : out = acc / 512
// T processed in chunks sized from ws_size (deterministic given ws_size).

typedef __attribute__((ext_vector_type(8))) __bf16 bf16x8;
typedef __attribute__((ext_vector_type(4))) __bf16 bf16x4;
typedef __attribute__((ext_vector_type(2))) __bf16 bf16x2;
typedef __attribute__((ext_vector_type(4))) float f32x4;
typedef __attribute__((ext_vector_type(2))) float f32x2;

#define MFMA(a, b, c) __builtin_amdgcn_mfma_f32_16x16x32_bf16(a, b, c, 0, 0, 0)

__device__ __forceinline__ float fsig(float v) {
  float e = __builtin_amdgcn_exp2f(v * -1.442695041f);
  return __builtin_amdgcn_rcpf(1.0f + e);
}
__device__ __forceinline__ float ftanh(float v) {
  float e = __builtin_amdgcn_exp2f(v * 2.885390082f);
  return 1.0f - 2.0f * __builtin_amdgcn_rcpf(1.0f + e);
}

// ---- workspace layout (bytes) ----
#define O_WIN 0u         // [1024][128] bf16  (W_ih rows 0-767, Wt rows 768-1023)
#define O_WHH 262144u    // [768][256] bf16
#define O_WO  655360u    // [64][256] bf16
#define O_WG  688128u    // [64][256] bf16
#define O_B1  720896u    // [1024] f32 folded bias
#define O_H   724992u    // [1024][256] f32 h state
#define O_ACC 1773568u   // [1024][64] f32 output accumulator
#define O_TIO 2035712u   // [TC][1024][64] bf16, then xi [TC][1024][768] bf16

__global__ void k1_prep(const float* __restrict__ Wih, const float* __restrict__ Wt,
                        const float* __restrict__ Whh, const float* __restrict__ Wo,
                        const float* __restrict__ Wg, const float* __restrict__ bih,
                        const float* __restrict__ bhh, const float* __restrict__ bt,
                        const float* __restrict__ h0, char* __restrict__ ws) {
  unsigned n = blockIdx.x * 256u + threadIdx.x;
  __bf16* win = (__bf16*)(ws + O_WIN);
  __bf16* whh = (__bf16*)(ws + O_WHH);
  __bf16* wo = (__bf16*)(ws + O_WO);
  __bf16* wg = (__bf16*)(ws + O_WG);
  float* b1 = (float*)(ws + O_B1);
  float* hb = (float*)(ws + O_H);
  float* ac = (float*)(ws + O_ACC);
  if (n < 98304u) win[n] = (__bf16)Wih[n];
  else if (n < 131072u) { unsigned i = n - 98304u; win[98304u + i] = (__bf16)Wt[i]; }
  else if (n < 327680u) { unsigned i = n - 131072u; whh[i] = (__bf16)Whh[i]; }
  else if (n < 344064u) { unsigned i = n - 327680u; wo[i] = (__bf16)Wo[i]; }
  else if (n < 360448u) { unsigned i = n - 344064u; wg[i] = (__bf16)Wg[i]; }
  else if (n < 361472u) {
    unsigned i = n - 360448u;
    float v = (i < 512u) ? (bih[i] + bhh[i]) : ((i < 768u) ? bih[i] : bt[i - 768u]);
    b1[i] = v;
  } else if (n < 623616u) { unsigned i = n - 361472u; hb[i] = h0[i]; }
  else if (n < 689152u) { unsigned i = n - 623616u; ac[i] = 0.0f; }
}

// ---------------- k2_xi: xi = x @ W_ih^T + bias1 (cols 0..767) ----------------
__global__ __launch_bounds__(256, 2) void k2_xi(
    const float* __restrict__ x, const __bf16* __restrict__ win,
    const float* __restrict__ b1, __bf16* __restrict__ xi, int t0, int tcbits) {
  extern __shared__ char sm2[];
  __bf16* Asm = (__bf16*)sm2;            // [128][136] bf16 (pad 8 -> 2-way-free banks)
  __bf16* Bsm = (__bf16*)(sm2 + 34816);  // [128][136]
  const int tid = threadIdx.x;
  const int lane = tid & 63, wv = tid >> 6;
  const int m0 = blockIdx.x * 128;
  const int tcm = (1 << tcbits) - 1;
  // stage A tile (x fp32 -> bf16)
#pragma unroll
  for (int rnd = 0; rnd < 16; ++rnd) {
    int row = rnd * 8 + (tid >> 5);
    int cr = m0 + row;
    int bb = cr >> tcbits, tt = cr & tcm;
    const float* xr = x + ((size_t)bb * 512 + (size_t)(t0 + tt)) * 128 + (tid & 31) * 4;
    float4 v = *(const float4*)xr;
    bf16x4 b4 = {(__bf16)v.x, (__bf16)v.y, (__bf16)v.z, (__bf16)v.w};
    *(bf16x4*)&Asm[row * 136 + (tid & 31) * 4] = b4;
  }
  for (int nc = 0; nc < 6; ++nc) {
    __syncthreads();
#pragma unroll
    for (int rnd = 0; rnd < 8; ++rnd) {
      int rr = rnd * 16 + (tid >> 4);
      uint4 w4 = *(const uint4*)(win + (size_t)(nc * 128 + rr) * 128 + (tid & 15) * 8);
      *(uint4*)&Bsm[rr * 136 + (tid & 15) * 8] = w4;
    }
    __syncthreads();
    f32x4 zv = {0.f, 0.f, 0.f, 0.f};
    f32x4 acc[2][8];
#pragma unroll
    for (int mi = 0; mi < 2; ++mi)
#pragma unroll
      for (int nt = 0; nt < 8; ++nt) acc[mi][nt] = zv;
#pragma unroll
    for (int kt = 0; kt < 4; ++kt) {
      bf16x8 a0 = *(const bf16x8*)&Asm[(wv * 32 + (lane & 15)) * 136 + kt * 32 + (lane >> 4) * 8];
      bf16x8 a1 = *(const bf16x8*)&Asm[(wv * 32 + 16 + (lane & 15)) * 136 + kt * 32 + (lane >> 4) * 8];
#pragma unroll
      for (int nt = 0; nt < 8; ++nt) {
        bf16x8 b = *(const bf16x8*)&Bsm[(nt * 16 + (lane & 15)) * 136 + kt * 32 + (lane >> 4) * 8];
        acc[0][nt] = MFMA(a0, b, acc[0][nt]);
        acc[1][nt] = MFMA(a1, b, acc[1][nt]);
      }
    }
    __syncthreads();  // done reading Bsm; reuse as store staging
#pragma unroll
    for (int nt = 0; nt < 8; ++nt) {
      float bv = b1[nc * 128 + nt * 16 + (lane & 15)];
#pragma unroll
      for (int mi = 0; mi < 2; ++mi)
#pragma unroll
        for (int r = 0; r < 4; ++r) {
          int rowb = wv * 32 + mi * 16 + (lane >> 4) * 4 + r;
          Bsm[rowb * 136 + nt * 16 + (lane & 15)] = (__bf16)(acc[mi][nt][r] + bv);
        }
    }
    __syncthreads();
#pragma unroll
    for (int rnd = 0; rnd < 8; ++rnd) {
      int row = rnd * 16 + (tid >> 4);
      int cr = m0 + row;
      int bb = cr >> tcbits, tt = cr & tcm;
      uint4 v = *(const uint4*)&Bsm[row * 136 + (tid & 15) * 8];
      *(uint4*)(xi + ((size_t)tt * 1024 + bb) * 768 + nc * 128 + (tid & 15) * 8) = v;
    }
  }
}

// -------- k2_tio: tio = silu(x@Wt^T + bt) @ Wo^T + bo --------
__global__ __launch_bounds__(256, 1) void k2_tio(
    const float* __restrict__ x, const __bf16* __restrict__ win,
    const __bf16* __restrict__ wo, const float* __restrict__ b1,
    const float* __restrict__ bo, __bf16* __restrict__ tio, int t0, int tcbits) {
  extern __shared__ char sm3[];
  __bf16* Asm = (__bf16*)sm3;             // [128][136]
  __bf16* Bsm = (__bf16*)(sm3 + 34816);   // [128][136] then [64][264]
  __bf16* Ti = (__bf16*)(sm3 + 69632);    // [128][264]
  const int tid = threadIdx.x;
  const int lane = tid & 63, wv = tid >> 6;
  const int m0 = blockIdx.x * 128;
  const int tcm = (1 << tcbits) - 1;
#pragma unroll
  for (int rnd = 0; rnd < 16; ++rnd) {
    int row = rnd * 8 + (tid >> 5);
    int cr = m0 + row;
    int bb = cr >> tcbits, tt = cr & tcm;
    const float* xr = x + ((size_t)bb * 512 + (size_t)(t0 + tt)) * 128 + (tid & 31) * 4;
    float4 v = *(const float4*)xr;
    bf16x4 b4 = {(__bf16)v.x, (__bf16)v.y, (__bf16)v.z, (__bf16)v.w};
    *(bf16x4*)&Asm[row * 136 + (tid & 31) * 4] = b4;
  }
  for (int nc = 0; nc < 2; ++nc) {
    __syncthreads();
#pragma unroll
    for (int rnd = 0; rnd < 8; ++rnd) {
      int rr = rnd * 16 + (tid >> 4);
      uint4 w4 = *(const uint4*)(win + (size_t)(98304 / 128 + nc * 128 + rr) * 128 + (tid & 15) * 8);
      *(uint4*)&Bsm[rr * 136 + (tid & 15) * 8] = w4;
    }
    __syncthreads();
    f32x4 zv = {0.f, 0.f, 0.f, 0.f};
    f32x4 acc[2][8];
#pragma unroll
    for (int mi = 0; mi < 2; ++mi)
#pragma unroll
      for (int nt = 0; nt < 8; ++nt) acc[mi][nt] = zv;
#pragma unroll
    for (int kt = 0; kt < 4; ++kt) {
      bf16x8 a0 = *(const bf16x8*)&Asm[(wv * 32 + (lane & 15)) * 136 + kt * 32 + (lane >> 4) * 8];
      bf16x8 a1 = *(const bf16x8*)&Asm[(wv * 32 + 16 + (lane & 15)) * 136 + kt * 32 + (lane >> 4) * 8];
#pragma unroll
      for (int nt = 0; nt < 8; ++nt) {
        bf16x8 b = *(const bf16x8*)&Bsm[(nt * 16 + (lane & 15)) * 136 + kt * 32 + (lane >> 4) * 8];
        acc[0][nt] = MFMA(a0, b, acc[0][nt]);
        acc[1][nt] = MFMA(a1, b, acc[1][nt]);
      }
    }
    // bias + silu -> Ti (no one reads Ti yet; barrier comes at loop top / below)
#pragma unroll
    for (int nt = 0; nt < 8; ++nt) {
      float bv = b1[768 + nc * 128 + nt * 16 + (lane & 15)];
#pragma unroll
      for (int mi = 0; mi < 2; ++mi)
#pragma unroll
        for (int r = 0; r < 4; ++r) {
          int rowb = wv * 32 + mi * 16 + (lane >> 4) * 4 + r;
          float s = acc[mi][nt][r] + bv;
          s = s * __builtin_amdgcn_rcpf(1.0f + __builtin_amdgcn_exp2f(s * -1.442695041f));
          Ti[rowb * 264 + nc * 128 + nt * 16 + (lane & 15)] = (__bf16)s;
        }
    }
  }
  __syncthreads();
  // stage Wo [64][256] -> Bsm [64][264]
  for (int i = tid; i < 2048; i += 256) {
    int row = i >> 5;
    int c8 = (i & 31) * 8;
    *(uint4*)&Bsm[row * 264 + c8] = *(const uint4*)(wo + row * 256 + c8);
  }
  __syncthreads();
  f32x4 zv = {0.f, 0.f, 0.f, 0.f};
  f32x4 acc2[2][4];
#pragma unroll
  for (int mi = 0; mi < 2; ++mi)
#pragma unroll
    for (int nt = 0; nt < 4; ++nt) acc2[mi][nt] = zv;
#pragma unroll
  for (int kt = 0; kt < 8; ++kt) {
    bf16x8 a0 = *(const bf16x8*)&Ti[(wv * 32 + (lane & 15)) * 264 + kt * 32 + (lane >> 4) * 8];
    bf16x8 a1 = *(const bf16x8*)&Ti[(wv * 32 + 16 + (lane & 15)) * 264 + kt * 32 + (lane >> 4) * 8];
#pragma unroll
    for (int nt = 0; nt < 4; ++nt) {
      bf16x8 b = *(const bf16x8*)&Bsm[(nt * 16 + (lane & 15)) * 264 + kt * 32 + (lane >> 4) * 8];
      acc2[0][nt] = MFMA(a0, b, acc2[0][nt]);
      acc2[1][nt] = MFMA(a1, b, acc2[1][nt]);
    }
  }
#pragma unroll
  for (int nt = 0; nt < 4; ++nt) {
    int col = nt * 16 + (lane & 15);
    float bv = bo[col];
#pragma unroll
    for (int mi = 0; mi < 2; ++mi)
#pragma unroll
      for (int r = 0; r < 4; ++r) {
        int rowb = wv * 32 + mi * 16 + (lane >> 4) * 4 + r;
        int cr = m0 + rowb;
        int bb = cr >> tcbits, tt = cr & tcm;
        tio[((size_t)tt * 1024 + bb) * 64 + col] = (__bf16)(acc2[mi][nt][r] + bv);
      }
  }
}

// ---------------- k3_rec v2: persistent GRU recurrence ----------------
// 256 blocks x 512 thr (8 waves = 2 waves/SIMD). Block owns batch rows b0..b0+3
// (M padded to 16). Wave wv owns h-cols [32wv,32wv+32): 2 p-tiles x 3 gates.
// ONE barrier/step: h double-buffered in LDS; gate redistribution is wave-local;
// proj/gate of h_{t-1} pipelined (pending-1 MFMA, pending-2 combine via pjb).
// LDS map: hb[2]   @0      : 2 x [16][264] bf16 = 16896
//          pre     @16896  : 8 waves x [12][36] f32 = 13824 (wave-local)
//          xib[2]  @30720  : 2 x 3328 bf16 = 13312 (4x768 xi + 4x64 tio)
//          pjb[2]  @44032  : 2 x [4][64] f32 = 2048 (pg exchange)
__global__ __launch_bounds__(512, 1) void k3_rec(
    const __bf16* __restrict__ xi, const __bf16* __restrict__ tio,
    const __bf16* __restrict__ whh, const __bf16* __restrict__ wo,
    const __bf16* __restrict__ wg, const float* __restrict__ bhn,
    const float* __restrict__ bg, float* __restrict__ hbuf,
    float* __restrict__ accb, int TC) {
  extern __shared__ char sm[];
  __bf16* hbase = (__bf16*)sm;
  float* preb = (float*)(sm + 16896);
  __bf16* xib = (__bf16*)(sm + 30720);
  float* pjb = (float*)(sm + 44032);
  const int tid = threadIdx.x;
  const int lane = tid & 63, wv = tid >> 6;
  const int b0 = blockIdx.x * 4;
  const int l15 = lane & 15, lg = lane >> 4;
  float* pre_w = preb + wv * 432;  // 12*36 floats per wave

  // register-resident W_hh fragments (compiler may stream the overflow from L2)
  bf16x8 wf[2][3][8];
#pragma unroll
  for (int p = 0; p < 2; ++p)
#pragma unroll
    for (int g = 0; g < 3; ++g)
#pragma unroll
      for (int kt = 0; kt < 8; ++kt) {
        int rowg = g * 256 + wv * 32 + p * 16 + l15;
        wf[p][g][kt] = *(const bf16x8*)(whh + (size_t)rowg * 256 + kt * 32 + lg * 8);
      }
  // proj fragments: waves 0-3 -> Wo tile wv, waves 4-7 -> Wg tile wv-4
  const __bf16* wsrc = (wv < 4) ? (wo + (size_t)(wv * 16 + l15) * 256)
                                : (wg + (size_t)((wv - 4) * 16 + l15) * 256);
  bf16x8 wpf[8];
#pragma unroll
  for (int kt = 0; kt < 8; ++kt) wpf[kt] = *(const bf16x8*)(wsrc + kt * 32 + lg * 8);

  float bhnp[2];
#pragma unroll
  for (int p = 0; p < 2; ++p) bhnp[p] = bhn[wv * 32 + p * 16 + l15];
  const float bgv = (wv >= 4) ? bg[(wv - 4) * 16 + l15] : 0.0f;

  // zero both h buffers (rows 4-15 must stay zero)
  for (int i = tid; i < 4224; i += 512) ((unsigned*)sm)[i] = 0u;
  __syncthreads();
  // init h: fp32 master regs (row=lg, cols wv*32 + 2*l15 + {0,1}) + bf16 in hb0
  const int row = lg;
  const int c2 = l15 * 2;
  float hreg[2];
  {
    const float* hp = hbuf + (size_t)(b0 + row) * 256 + wv * 32 + c2;
    hreg[0] = hp[0];
    hreg[1] = hp[1];
    bf16x2 h2 = {(__bf16)hreg[0], (__bf16)hreg[1]};
    *(bf16x2*)&hbase[row * 264 + wv * 32 + c2] = h2;
  }
  float oacc[4] = {0.f, 0.f, 0.f, 0.f};
  if (wv < 4 && lane < 16) {
#pragma unroll
    for (int r = 0; r < 4; ++r) oacc[r] = accb[(size_t)(b0 + r) * 64 + wv * 16 + lane];
  }
  // stage slice t=0 (832 uint2 total)
  {
    const uint2* s = (const uint2*)(xi + (size_t)b0 * 768);
    uint2* d = (uint2*)xib;
    d[tid] = s[tid];
    if (tid < 256) d[512 + tid] = s[512 + tid];
    if (tid < 64) d[768 + tid] = ((const uint2*)(tio + (size_t)b0 * 64))[tid];
  }
  float tioA[4] = {0.f, 0.f, 0.f, 0.f}, tioB[4] = {0.f, 0.f, 0.f, 0.f};
  f32x4 poA = {0.f, 0.f, 0.f, 0.f};
  __syncthreads();

#pragma unroll 1
  for (int t = 0; t < TC; ++t) {
    const int cur = t & 1, nxt = cur ^ 1;
    const __bf16* hcur = hbase + cur * 4224;
    __bf16* hnxt = hbase + nxt * 4224;
    const __bf16* xc = xib + cur * 3328;
    // prefetch slice t+1 into regs (committed before the barrier)
    int tn = (t + 1 < TC) ? (t + 1) : t;
    uint2 pf0, pf1, pft;
    {
      const uint2* s = (const uint2*)(xi + ((size_t)tn * 1024 + b0) * 768);
      pf0 = s[tid];
      if (tid < 256) pf1 = s[512 + tid];
      if (tid < 64) pft = ((const uint2*)(tio + ((size_t)tn * 1024 + b0) * 64))[tid];
    }
    // h_{t-1} fragments (shared by proj AND hh matmuls)
    bf16x8 afr[8];
#pragma unroll
    for (int kt = 0; kt < 8; ++kt)
      afr[kt] = *(const bf16x8*)&hcur[l15 * 264 + kt * 32 + lg * 8];
    // pending combine: emit output term for H_{t-2}
    if (t >= 2 && wv < 4 && lane < 16) {
      const float* pj = pjb + ((t - 1) & 1) * 256;
#pragma unroll
      for (int r = 0; r < 4; ++r)
        oacc[r] += (poA[r] + tioA[r]) * fsig(pj[r * 64 + wv * 16 + lane]);
    }
    // proj MFMAs on h_{t-1} (waves<4: po, waves>=4: pg seeded with bg)
    f32x4 pN = {bgv, bgv, bgv, bgv};
#pragma unroll
    for (int kt = 0; kt < 8; ++kt) pN = MFMA(afr[kt], wpf[kt], pN);
    // hh = h_{t-1} @ W_hh^T (n-gate pre-seeded with b_hh_n); wave-local pre store
#pragma unroll
    for (int p = 0; p < 2; ++p) {
      f32x4 ar = {0.f, 0.f, 0.f, 0.f}, az = {0.f, 0.f, 0.f, 0.f};
      f32x4 an = {bhnp[p], bhnp[p], bhnp[p], bhnp[p]};
#pragma unroll
      for (int kt = 0; kt < 8; ++kt) {
        ar = MFMA(afr[kt], wf[p][0][kt], ar);
        az = MFMA(afr[kt], wf[p][1][kt], az);
        an = MFMA(afr[kt], wf[p][2][kt], an);
      }
      if (lane < 16) {
#pragma unroll
        for (int r = 0; r < 4; ++r) {
          pre_w[(0 + r) * 36 + p * 16 + lane] = ar[r];
          pre_w[(4 + r) * 36 + p * 16 + lane] = az[r];
          pre_w[(8 + r) * 36 + p * 16 + lane] = an[r];
        }
      }
    }
    // gating: all 64 lanes, 2 h-elems each, wave-local redistribution (no barrier)
    {
      f32x2 hr = *(const f32x2*)&pre_w[(0 + row) * 36 + c2];
      f32x2 hz = *(const f32x2*)&pre_w[(4 + row) * 36 + c2];
      f32x2 hn = *(const f32x2*)&pre_w[(8 + row) * 36 + c2];
      bf16x2 xr2 = *(const bf16x2*)&xc[row * 768 + wv * 32 + c2];
      bf16x2 xz2 = *(const bf16x2*)&xc[row * 768 + 256 + wv * 32 + c2];
      bf16x2 xn2 = *(const bf16x2*)&xc[row * 768 + 512 + wv * 32 + c2];
#pragma unroll
      for (int j = 0; j < 2; ++j) {
        float r_ = fsig((float)xr2[j] + hr[j]);
        float z_ = fsig((float)xz2[j] + hz[j]);
        float n_ = ftanh((float)xn2[j] + r_ * hn[j]);
        hreg[j] = n_ + z_ * (hreg[j] - n_);
      }
      bf16x2 h2 = {(__bf16)hreg[0], (__bf16)hreg[1]};
      *(bf16x2*)&hnxt[row * 264 + wv * 32 + c2] = h2;
    }
    // publish pg for next-iter combine (double-buffered -> race-free)
    if (wv >= 4 && lane < 16) {
      float* pj = pjb + cur * 256;
#pragma unroll
      for (int r = 0; r < 4; ++r) pj[r * 64 + (wv - 4) * 16 + lane] = pN[r];
    }
    // tio register chain (depth 2)
    if (wv < 4 && lane < 16) {
#pragma unroll
      for (int r = 0; r < 4; ++r) {
        tioA[r] = tioB[r];
        tioB[r] = (float)xc[3072 + r * 64 + wv * 16 + lane];
      }
    }
    poA = pN;
    // commit prefetched slice t+1
    {
      uint2* d = (uint2*)(xib + nxt * 3328);
      d[tid] = pf0;
      if (tid < 256) d[512 + tid] = pf1;
      if (tid < 64) d[768 + tid] = pft;
    }
    __syncthreads();
  }
  // epilogue (a): combine H_{TC-2}
  if (TC >= 2 && wv < 4 && lane < 16) {
    const float* pj = pjb + ((TC - 1) & 1) * 256;
#pragma unroll
    for (int r = 0; r < 4; ++r)
      oacc[r] += (poA[r] + tioA[r]) * fsig(pj[r * 64 + wv * 16 + lane]);
  }
  // epilogue (b): proj + combine H_{TC-1}
  {
    const __bf16* hcur = hbase + (TC & 1) * 4224;
    bf16x8 af[8];
#pragma unroll
    for (int kt = 0; kt < 8; ++kt)
      af[kt] = *(const bf16x8*)&hcur[l15 * 264 + kt * 32 + lg * 8];
    f32x4 pN = {bgv, bgv, bgv, bgv};
#pragma unroll
    for (int kt = 0; kt < 8; ++kt) pN = MFMA(af[kt], wpf[kt], pN);
    if (wv >= 4 && lane < 16) {
      float* pj = pjb + (TC & 1) * 256;
#pragma unroll
      for (int r = 0; r < 4; ++r) pj[r * 64 + (wv - 4) * 16 + lane] = pN[r];
    }
    __syncthreads();
    if (wv < 4 && lane < 16) {
      const float* pj = pjb + (TC & 1) * 256;
#pragma unroll
      for (int r = 0; r < 4; ++r)
        oacc[r] += (pN[r] + tioB[r]) * fsig(pj[r * 64 + wv * 16 + lane]);
    }
  }
  // writeback state
  {
    float* hp = hbuf + (size_t)(b0 + row) * 256 + wv * 32 + c2;
    hp[0] = hreg[0];
    hp[1] = hreg[1];
  }
  if (wv < 4 && lane < 16) {
#pragma unroll
    for (int r = 0; r < 4; ++r) accb[(size_t)(b0 + r) * 64 + wv * 16 + lane] = oacc[r];
  }
}

__global__ void k4_out(const float* __restrict__ accb, float* __restrict__ out) {
  int i = blockIdx.x * 256 + threadIdx.x;
  out[i] = accb[i] * (1.0f / 512.0f);
}

extern "C" void kernel_launch(void* const* d_in, const int* in_sizes, int n_in,
                              void* d_out, int out_size, void* d_ws, size_t ws_size,
                              hipStream_t stream) {
  const float* x = (const float*)d_in[0];
  const float* h0 = (const float*)d_in[1];
  const float* Wih = (const float*)d_in[2];
  const float* bih = (const float*)d_in[3];
  const float* Whh = (const float*)d_in[4];
  const float* bhh = (const float*)d_in[5];
  const float* Wt = (const float*)d_in[6];
  const float* bt = (const float*)d_in[7];
  const float* Wo = (const float*)d_in[8];
  const float* bo = (const float*)d_in[9];
  const float* Wg = (const float*)d_in[10];
  const float* bg = (const float*)d_in[11];
  float* out = (float*)d_out;
  char* ws = (char*)d_ws;

  // pick largest power-of-2 time-chunk that fits ws
  int TC = 512;
  while (TC > 1 && (2035712ull + (size_t)TC * 1703936ull) > ws_size) TC >>= 1;
  int tcbits = 0;
  while ((1 << tcbits) != TC) ++tcbits;

  __bf16* win = (__bf16*)(ws + O_WIN);
  __bf16* whhb = (__bf16*)(ws + O_WHH);
  __bf16* wob = (__bf16*)(ws + O_WO);
  __bf16* wgb = (__bf16*)(ws + O_WG);
  float* b1 = (float*)(ws + O_B1);
  float* hbuf = (float*)(ws + O_H);
  float* accb = (float*)(ws + O_ACC);
  __bf16* tioc = (__bf16*)(ws + O_TIO);
  __bf16* xic = (__bf16*)(ws + O_TIO + (size_t)TC * 131072u);

  (void)hipFuncSetAttribute((const void*)k2_xi, hipFuncAttributeMaxDynamicSharedMemorySize, 69632);
  (void)hipFuncSetAttribute((const void*)k2_tio, hipFuncAttributeMaxDynamicSharedMemorySize, 137216);
  (void)hipFuncSetAttribute((const void*)k3_rec, hipFuncAttributeMaxDynamicSharedMemorySize, 46080);

  k1_prep<<<2692, 256, 0, stream>>>(Wih, Wt, Whh, Wo, Wg, bih, bhh, bt, h0, ws);
  int nch = 512 / TC;
  for (int c = 0; c < nch; ++c) {
    int t0 = c * TC;
    k2_xi<<<8 * TC, 256, 69632, stream>>>(x, win, b1, xic, t0, tcbits);
    k2_tio<<<8 * TC, 256, 137216, stream>>>(x, win, wob, b1, bo, tioc, t0, tcbits);
    k3_rec<<<256, 512, 46080, stream>>>(xic, tioc, whhb, wob, wgb, bhh + 512, bg, hbuf, accb, TC);
  }
  k4_out<<<256, 256, 0, stream>>>(accb, out);
}

// Round 2
// 2158.580 us; speedup vs baseline: 1.9267x; 1.9267x over previous
//
#include <hip/hip_runtime.h>
#include <hip/hip_bf16.h>

// GRU-scan model, MI355X. Strategy:
//  k1_prep : cvt weights to bf16, fold biases, init h/acc buffers (in ws)
//  k2_xi   : xi[t][b][3H] = x@W_ih^T + (b_ih + b_hh_{r,z} fold)   (bf16, tiled MFMA)
//  k2_tio  : tio[t][b][O] = silu(x@Wt^T + bt)@Wo^T + bo           (bf16, fused 2-stage)
//  k3_rec  : persistent recurrence v3: 256 blocks x 256 thr (4 waves = 1/SIMD,
//            full 512-reg budget -> W_hh register-resident, the load-bearing
//            property). ONE barrier/step via h double-buffer; wave-local gate
//            redistribution (no cross-wave pre barrier); proj/gate of h_{t-1}
//            reuses the same A-fragments as the hh matmul (pending combine,
//            wave-local, depth-1 tio chain).
//  k4_out  : out = acc / 512
// T processed in chunks sized from ws_size (deterministic given ws_size).

typedef __attribute__((ext_vector_type(8))) __bf16 bf16x8;
typedef __attribute__((ext_vector_type(4))) __bf16 bf16x4;
typedef __attribute__((ext_vector_type(2))) __bf16 bf16x2;
typedef __attribute__((ext_vector_type(4))) float f32x4;

#define MFMA(a, b, c) __builtin_amdgcn_mfma_f32_16x16x32_bf16(a, b, c, 0, 0, 0)

__device__ __forceinline__ float fsig(float v) {
  float e = __builtin_amdgcn_exp2f(v * -1.442695041f);
  return __builtin_amdgcn_rcpf(1.0f + e);
}
__device__ __forceinline__ float ftanh(float v) {
  float e = __builtin_amdgcn_exp2f(v * 2.885390082f);
  return 1.0f - 2.0f * __builtin_amdgcn_rcpf(1.0f + e);
}

// ---- workspace layout (bytes) ----
#define O_WIN 0u         // [1024][128] bf16  (W_ih rows 0-767, Wt rows 768-1023)
#define O_WHH 262144u    // [768][256] bf16
#define O_WO  655360u    // [64][256] bf16
#define O_WG  688128u    // [64][256] bf16
#define O_B1  720896u    // [1024] f32 folded bias
#define O_H   724992u    // [1024][256] f32 h state
#define O_ACC 1773568u   // [1024][64] f32 output accumulator
#define O_TIO 2035712u   // [TC][1024][64] bf16, then xi [TC][1024][768] bf16

__global__ void k1_prep(const float* __restrict__ Wih, const float* __restrict__ Wt,
                        const float* __restrict__ Whh, const float* __restrict__ Wo,
                        const float* __restrict__ Wg, const float* __restrict__ bih,
                        const float* __restrict__ bhh, const float* __restrict__ bt,
                        const float* __restrict__ h0, char* __restrict__ ws) {
  unsigned n = blockIdx.x * 256u + threadIdx.x;
  __bf16* win = (__bf16*)(ws + O_WIN);
  __bf16* whh = (__bf16*)(ws + O_WHH);
  __bf16* wo = (__bf16*)(ws + O_WO);
  __bf16* wg = (__bf16*)(ws + O_WG);
  float* b1 = (float*)(ws + O_B1);
  float* hb = (float*)(ws + O_H);
  float* ac = (float*)(ws + O_ACC);
  if (n < 98304u) win[n] = (__bf16)Wih[n];
  else if (n < 131072u) { unsigned i = n - 98304u; win[98304u + i] = (__bf16)Wt[i]; }
  else if (n < 327680u) { unsigned i = n - 131072u; whh[i] = (__bf16)Whh[i]; }
  else if (n < 344064u) { unsigned i = n - 327680u; wo[i] = (__bf16)Wo[i]; }
  else if (n < 360448u) { unsigned i = n - 344064u; wg[i] = (__bf16)Wg[i]; }
  else if (n < 361472u) {
    unsigned i = n - 360448u;
    float v = (i < 512u) ? (bih[i] + bhh[i]) : ((i < 768u) ? bih[i] : bt[i - 768u]);
    b1[i] = v;
  } else if (n < 623616u) { unsigned i = n - 361472u; hb[i] = h0[i]; }
  else if (n < 689152u) { unsigned i = n - 623616u; ac[i] = 0.0f; }
}

// ---------------- k2_xi: xi = x @ W_ih^T + bias1 (cols 0..767) ----------------
__global__ __launch_bounds__(256, 2) void k2_xi(
    const float* __restrict__ x, const __bf16* __restrict__ win,
    const float* __restrict__ b1, __bf16* __restrict__ xi, int t0, int tcbits) {
  extern __shared__ char sm2[];
  __bf16* Asm = (__bf16*)sm2;            // [128][136] bf16 (pad 8 -> 2-way-free banks)
  __bf16* Bsm = (__bf16*)(sm2 + 34816);  // [128][136]
  const int tid = threadIdx.x;
  const int lane = tid & 63, wv = tid >> 6;
  const int m0 = blockIdx.x * 128;
  const int tcm = (1 << tcbits) - 1;
  // stage A tile (x fp32 -> bf16)
#pragma unroll
  for (int rnd = 0; rnd < 16; ++rnd) {
    int row = rnd * 8 + (tid >> 5);
    int cr = m0 + row;
    int bb = cr >> tcbits, tt = cr & tcm;
    const float* xr = x + ((size_t)bb * 512 + (size_t)(t0 + tt)) * 128 + (tid & 31) * 4;
    float4 v = *(const float4*)xr;
    bf16x4 b4 = {(__bf16)v.x, (__bf16)v.y, (__bf16)v.z, (__bf16)v.w};
    *(bf16x4*)&Asm[row * 136 + (tid & 31) * 4] = b4;
  }
  for (int nc = 0; nc < 6; ++nc) {
    __syncthreads();
#pragma unroll
    for (int rnd = 0; rnd < 8; ++rnd) {
      int rr = rnd * 16 + (tid >> 4);
      uint4 w4 = *(const uint4*)(win + (size_t)(nc * 128 + rr) * 128 + (tid & 15) * 8);
      *(uint4*)&Bsm[rr * 136 + (tid & 15) * 8] = w4;
    }
    __syncthreads();
    f32x4 zv = {0.f, 0.f, 0.f, 0.f};
    f32x4 acc[2][8];
#pragma unroll
    for (int mi = 0; mi < 2; ++mi)
#pragma unroll
      for (int nt = 0; nt < 8; ++nt) acc[mi][nt] = zv;
#pragma unroll
    for (int kt = 0; kt < 4; ++kt) {
      bf16x8 a0 = *(const bf16x8*)&Asm[(wv * 32 + (lane & 15)) * 136 + kt * 32 + (lane >> 4) * 8];
      bf16x8 a1 = *(const bf16x8*)&Asm[(wv * 32 + 16 + (lane & 15)) * 136 + kt * 32 + (lane >> 4) * 8];
#pragma unroll
      for (int nt = 0; nt < 8; ++nt) {
        bf16x8 b = *(const bf16x8*)&Bsm[(nt * 16 + (lane & 15)) * 136 + kt * 32 + (lane >> 4) * 8];
        acc[0][nt] = MFMA(a0, b, acc[0][nt]);
        acc[1][nt] = MFMA(a1, b, acc[1][nt]);
      }
    }
    __syncthreads();  // done reading Bsm; reuse as store staging
#pragma unroll
    for (int nt = 0; nt < 8; ++nt) {
      float bv = b1[nc * 128 + nt * 16 + (lane & 15)];
#pragma unroll
      for (int mi = 0; mi < 2; ++mi)
#pragma unroll
        for (int r = 0; r < 4; ++r) {
          int rowb = wv * 32 + mi * 16 + (lane >> 4) * 4 + r;
          Bsm[rowb * 136 + nt * 16 + (lane & 15)] = (__bf16)(acc[mi][nt][r] + bv);
        }
    }
    __syncthreads();
#pragma unroll
    for (int rnd = 0; rnd < 8; ++rnd) {
      int row = rnd * 16 + (tid >> 4);
      int cr = m0 + row;
      int bb = cr >> tcbits, tt = cr & tcm;
      uint4 v = *(const uint4*)&Bsm[row * 136 + (tid & 15) * 8];
      *(uint4*)(xi + ((size_t)tt * 1024 + bb) * 768 + nc * 128 + (tid & 15) * 8) = v;
    }
  }
}

// -------- k2_tio: tio = silu(x@Wt^T + bt) @ Wo^T + bo --------
__global__ __launch_bounds__(256, 1) void k2_tio(
    const float* __restrict__ x, const __bf16* __restrict__ win,
    const __bf16* __restrict__ wo, const float* __restrict__ b1,
    const float* __restrict__ bo, __bf16* __restrict__ tio, int t0, int tcbits) {
  extern __shared__ char sm3[];
  __bf16* Asm = (__bf16*)sm3;             // [128][136]
  __bf16* Bsm = (__bf16*)(sm3 + 34816);   // [128][136] then [64][264]
  __bf16* Ti = (__bf16*)(sm3 + 69632);    // [128][264]
  const int tid = threadIdx.x;
  const int lane = tid & 63, wv = tid >> 6;
  const int m0 = blockIdx.x * 128;
  const int tcm = (1 << tcbits) - 1;
#pragma unroll
  for (int rnd = 0; rnd < 16; ++rnd) {
    int row = rnd * 8 + (tid >> 5);
    int cr = m0 + row;
    int bb = cr >> tcbits, tt = cr & tcm;
    const float* xr = x + ((size_t)bb * 512 + (size_t)(t0 + tt)) * 128 + (tid & 31) * 4;
    float4 v = *(const float4*)xr;
    bf16x4 b4 = {(__bf16)v.x, (__bf16)v.y, (__bf16)v.z, (__bf16)v.w};
    *(bf16x4*)&Asm[row * 136 + (tid & 31) * 4] = b4;
  }
  for (int nc = 0; nc < 2; ++nc) {
    __syncthreads();
#pragma unroll
    for (int rnd = 0; rnd < 8; ++rnd) {
      int rr = rnd * 16 + (tid >> 4);
      uint4 w4 = *(const uint4*)(win + (size_t)(98304 / 128 + nc * 128 + rr) * 128 + (tid & 15) * 8);
      *(uint4*)&Bsm[rr * 136 + (tid & 15) * 8] = w4;
    }
    __syncthreads();
    f32x4 zv = {0.f, 0.f, 0.f, 0.f};
    f32x4 acc[2][8];
#pragma unroll
    for (int mi = 0; mi < 2; ++mi)
#pragma unroll
      for (int nt = 0; nt < 8; ++nt) acc[mi][nt] = zv;
#pragma unroll
    for (int kt = 0; kt < 4; ++kt) {
      bf16x8 a0 = *(const bf16x8*)&Asm[(wv * 32 + (lane & 15)) * 136 + kt * 32 + (lane >> 4) * 8];
      bf16x8 a1 = *(const bf16x8*)&Asm[(wv * 32 + 16 + (lane & 15)) * 136 + kt * 32 + (lane >> 4) * 8];
#pragma unroll
      for (int nt = 0; nt < 8; ++nt) {
        bf16x8 b = *(const bf16x8*)&Bsm[(nt * 16 + (lane & 15)) * 136 + kt * 32 + (lane >> 4) * 8];
        acc[0][nt] = MFMA(a0, b, acc[0][nt]);
        acc[1][nt] = MFMA(a1, b, acc[1][nt]);
      }
    }
    // bias + silu -> Ti (no one reads Ti yet; barrier comes at loop top / below)
#pragma unroll
    for (int nt = 0; nt < 8; ++nt) {
      float bv = b1[768 + nc * 128 + nt * 16 + (lane & 15)];
#pragma unroll
      for (int mi = 0; mi < 2; ++mi)
#pragma unroll
        for (int r = 0; r < 4; ++r) {
          int rowb = wv * 32 + mi * 16 + (lane >> 4) * 4 + r;
          float s = acc[mi][nt][r] + bv;
          s = s * __builtin_amdgcn_rcpf(1.0f + __builtin_amdgcn_exp2f(s * -1.442695041f));
          Ti[rowb * 264 + nc * 128 + nt * 16 + (lane & 15)] = (__bf16)s;
        }
    }
  }
  __syncthreads();
  // stage Wo [64][256] -> Bsm [64][264]
  for (int i = tid; i < 2048; i += 256) {
    int row = i >> 5;
    int c8 = (i & 31) * 8;
    *(uint4*)&Bsm[row * 264 + c8] = *(const uint4*)(wo + row * 256 + c8);
  }
  __syncthreads();
  f32x4 zv = {0.f, 0.f, 0.f, 0.f};
  f32x4 acc2[2][4];
#pragma unroll
  for (int mi = 0; mi < 2; ++mi)
#pragma unroll
    for (int nt = 0; nt < 4; ++nt) acc2[mi][nt] = zv;
#pragma unroll
  for (int kt = 0; kt < 8; ++kt) {
    bf16x8 a0 = *(const bf16x8*)&Ti[(wv * 32 + (lane & 15)) * 264 + kt * 32 + (lane >> 4) * 8];
    bf16x8 a1 = *(const bf16x8*)&Ti[(wv * 32 + 16 + (lane & 15)) * 264 + kt * 32 + (lane >> 4) * 8];
#pragma unroll
    for (int nt = 0; nt < 4; ++nt) {
      bf16x8 b = *(const bf16x8*)&Bsm[(nt * 16 + (lane & 15)) * 264 + kt * 32 + (lane >> 4) * 8];
      acc2[0][nt] = MFMA(a0, b, acc2[0][nt]);
      acc2[1][nt] = MFMA(a1, b, acc2[1][nt]);
    }
  }
#pragma unroll
  for (int nt = 0; nt < 4; ++nt) {
    int col = nt * 16 + (lane & 15);
    float bv = bo[col];
#pragma unroll
    for (int mi = 0; mi < 2; ++mi)
#pragma unroll
      for (int r = 0; r < 4; ++r) {
        int rowb = wv * 32 + mi * 16 + (lane >> 4) * 4 + r;
        int cr = m0 + rowb;
        int bb = cr >> tcbits, tt = cr & tcm;
        tio[((size_t)tt * 1024 + bb) * 64 + col] = (__bf16)(acc2[mi][nt][r] + bv);
      }
  }
}

// ---------------- k3_rec v3: persistent GRU recurrence ----------------
// 256 blocks x 256 thr (4 waves = 1 wave/SIMD -> full 512-reg budget/wave).
// Block owns batch rows b0..b0+3 (M padded to 16). Wave wv owns h-cols
// [64wv,64wv+64): 4 p-tiles x 3 gates; W_hh frags register-resident
// (12 tiles x 8 kfrags x 4 VGPR = 384 regs incl. AGPR side of unified file).
// ONE barrier/step: h double-buffered; pre is wave-local (lgkmcnt only);
// proj/gate of h_{t-1} reuses afr (pending combine, wave-local, depth-1 tio).
// LDS map: hb[2] @0     : 2 x [16][264] bf16 = 16896
//          pre   @16896 : 4 waves x [3][4][68] f32 = 13056
//          xib[2]@29952 : 2 x 3328 bf16 = 13312 (4x768 xi + 4x64 tio)
//          wow   @43264 : [128][264] bf16 = 67584 (Wo rows 0-63, Wg 64-127)
// total 110848
__global__ __launch_bounds__(256, 1) void k3_rec(
    const __bf16* __restrict__ xi, const __bf16* __restrict__ tio,
    const __bf16* __restrict__ whh, const __bf16* __restrict__ wo,
    const __bf16* __restrict__ wg, const float* __restrict__ bhn,
    const float* __restrict__ bg, float* __restrict__ hbuf,
    float* __restrict__ accb, int TC) {
  extern __shared__ char sm[];
  __bf16* hbase = (__bf16*)sm;
  float* preb = (float*)(sm + 16896);
  __bf16* xib = (__bf16*)(sm + 29952);
  __bf16* wow = (__bf16*)(sm + 43264);
  const int tid = threadIdx.x;
  const int lane = tid & 63, wv = tid >> 6;
  const int b0 = blockIdx.x * 4;
  const int l15 = lane & 15, lg = lane >> 4;
  float* pre_w = preb + wv * 816;  // [3][4][68] f32 per wave

  // register-resident W_hh fragments (load-bearing: must NOT be re-streamed)
  bf16x8 wf[4][3][8];
#pragma unroll
  for (int p = 0; p < 4; ++p)
#pragma unroll
    for (int g = 0; g < 3; ++g)
#pragma unroll
      for (int kt = 0; kt < 8; ++kt) {
        int rowg = g * 256 + wv * 64 + p * 16 + l15;
        wf[p][g][kt] = *(const bf16x8*)(whh + (size_t)rowg * 256 + kt * 32 + lg * 8);
      }
  // stage Wo/Wg -> wow
  for (int i = tid; i < 4096; i += 256) {
    int row = i >> 5;
    int c8 = (i & 31) * 8;
    const __bf16* srcw = (row < 64) ? (wo + row * 256 + c8) : (wg + (row - 64) * 256 + c8);
    *(uint4*)&wow[row * 264 + c8] = *(const uint4*)srcw;
  }
  // zero both h buffers (rows 4-15 must stay zero)
  for (int i = tid; i < 4224; i += 256) ((unsigned*)sm)[i] = 0u;
  __syncthreads();
  // fp32 master h: thread owns (row=lg, cols wv*64 + 4*l15 .. +3)
  const int row = lg;
  const int c4 = l15 * 4;
  float hreg[4];
  {
    f32x4 h4 = *(const f32x4*)(hbuf + (size_t)(b0 + row) * 256 + wv * 64 + c4);
    hreg[0] = h4[0]; hreg[1] = h4[1]; hreg[2] = h4[2]; hreg[3] = h4[3];
    bf16x4 hb = {(__bf16)h4[0], (__bf16)h4[1], (__bf16)h4[2], (__bf16)h4[3]};
    *(bf16x4*)&hbase[row * 264 + wv * 64 + c4] = hb;
  }
  float bhnp[4];
#pragma unroll
  for (int p = 0; p < 4; ++p) bhnp[p] = bhn[wv * 64 + p * 16 + l15];
  const float bgv = bg[wv * 16 + l15];
  float oacc[4] = {0.f, 0.f, 0.f, 0.f};
  if (lane < 16) {
#pragma unroll
    for (int r = 0; r < 4; ++r) oacc[r] = accb[(size_t)(b0 + r) * 64 + wv * 16 + lane];
  }
  // stage slice t=0 (832 uint2 total)
  {
    const uint2* s0 = (const uint2*)(xi + (size_t)b0 * 768);
    uint2* d0 = (uint2*)xib;
    d0[tid] = s0[tid]; d0[tid + 256] = s0[tid + 256]; d0[tid + 512] = s0[tid + 512];
    if (tid < 64) ((uint2*)(xib + 3072))[tid] = ((const uint2*)(tio + (size_t)b0 * 64))[tid];
  }
  float tioR[4] = {0.f, 0.f, 0.f, 0.f};
  __syncthreads();

#pragma unroll 1
  for (int t = 0; t < TC; ++t) {
    const int cur = t & 1, nxt = cur ^ 1;
    const __bf16* hcur = hbase + cur * 4224;
    __bf16* hnxt = hbase + nxt * 4224;
    const __bf16* xc = xib + cur * 3328;
    // prefetch slice t+1 into regs (committed before the barrier)
    int tn = (t + 1 < TC) ? (t + 1) : t;
    uint2 pf0, pf1, pf2, pft;
    {
      const uint2* s = (const uint2*)(xi + ((size_t)tn * 1024 + b0) * 768);
      pf0 = s[tid]; pf1 = s[tid + 256]; pf2 = s[tid + 512];
      if (tid < 64) pft = ((const uint2*)(tio + ((size_t)tn * 1024 + b0) * 64))[tid];
    }
    // h_{t-1} fragments (shared by hh AND proj matmuls)
    bf16x8 afr[8];
#pragma unroll
    for (int kt = 0; kt < 8; ++kt)
      afr[kt] = *(const bf16x8*)&hcur[l15 * 264 + kt * 32 + lg * 8];
    // hh = h_{t-1} @ W_hh^T (n-gate pre-seeded with b_hh_n); wave-local pre
#pragma unroll
    for (int p = 0; p < 4; ++p) {
      f32x4 ar = {0.f, 0.f, 0.f, 0.f}, az = {0.f, 0.f, 0.f, 0.f};
      f32x4 an = {bhnp[p], bhnp[p], bhnp[p], bhnp[p]};
#pragma unroll
      for (int kt = 0; kt < 8; ++kt) {
        ar = MFMA(afr[kt], wf[p][0][kt], ar);
        az = MFMA(afr[kt], wf[p][1][kt], az);
        an = MFMA(afr[kt], wf[p][2][kt], an);
      }
      if (lane < 16) {
#pragma unroll
        for (int r = 0; r < 4; ++r) {
          pre_w[r * 68 + p * 16 + lane] = ar[r];
          pre_w[272 + r * 68 + p * 16 + lane] = az[r];
          pre_w[544 + r * 68 + p * 16 + lane] = an[r];
        }
      }
    }
    // gating: wave-local (owns 4 rows x 64 cols; 4 elems/thread), no barrier
    {
      f32x4 hr = *(const f32x4*)&pre_w[row * 68 + c4];
      f32x4 hz = *(const f32x4*)&pre_w[272 + row * 68 + c4];
      f32x4 hn = *(const f32x4*)&pre_w[544 + row * 68 + c4];
      bf16x4 xr4 = *(const bf16x4*)&xc[row * 768 + wv * 64 + c4];
      bf16x4 xz4 = *(const bf16x4*)&xc[row * 768 + 256 + wv * 64 + c4];
      bf16x4 xn4 = *(const bf16x4*)&xc[row * 768 + 512 + wv * 64 + c4];
#pragma unroll
      for (int j = 0; j < 4; ++j) {
        float r_ = fsig((float)xr4[j] + hr[j]);
        float z_ = fsig((float)xz4[j] + hz[j]);
        float n_ = ftanh((float)xn4[j] + r_ * hn[j]);
        hreg[j] = n_ + z_ * (hreg[j] - n_);
      }
      bf16x4 hb = {(__bf16)hreg[0], (__bf16)hreg[1], (__bf16)hreg[2], (__bf16)hreg[3]};
      *(bf16x4*)&hnxt[row * 264 + wv * 64 + c4] = hb;
    }
    // proj/gate on h_{t-1} (reuses afr): out-cols 16wv..16wv+15, wave-local
    {
      f32x4 po = {0.f, 0.f, 0.f, 0.f};
      f32x4 pg = {bgv, bgv, bgv, bgv};
#pragma unroll
      for (int kt = 0; kt < 8; ++kt) {
        bf16x8 bfo = *(const bf16x8*)&wow[(wv * 16 + l15) * 264 + kt * 32 + lg * 8];
        bf16x8 bfg = *(const bf16x8*)&wow[(64 + wv * 16 + l15) * 264 + kt * 32 + lg * 8];
        po = MFMA(afr[kt], bfo, po);
        pg = MFMA(afr[kt], bfg, pg);
      }
      if (t >= 1 && lane < 16) {
#pragma unroll
        for (int r = 0; r < 4; ++r)
          oacc[r] += (po[r] + tioR[r]) * fsig(pg[r]);  // tio already includes bo
      }
    }
    // tio chain for slice t (used next iter / epilogue)
    if (lane < 16) {
#pragma unroll
      for (int r = 0; r < 4; ++r) tioR[r] = (float)xc[3072 + r * 64 + wv * 16 + lane];
    }
    // commit prefetched slice t+1
    {
      uint2* d = (uint2*)(xib + nxt * 3328);
      d[tid] = pf0; d[tid + 256] = pf1; d[tid + 512] = pf2;
      if (tid < 64) ((uint2*)(xib + nxt * 3328 + 3072))[tid] = pft;
    }
    __syncthreads();  // h_t + next slice visible
  }
  // epilogue: proj + combine for h_{TC-1} (in buffer TC&1), tioR holds slice TC-1
  {
    const __bf16* hcur = hbase + (TC & 1) * 4224;
    bf16x8 af[8];
#pragma unroll
    for (int kt = 0; kt < 8; ++kt)
      af[kt] = *(const bf16x8*)&hcur[l15 * 264 + kt * 32 + lg * 8];
    f32x4 po = {0.f, 0.f, 0.f, 0.f};
    f32x4 pg = {bgv, bgv, bgv, bgv};
#pragma unroll
    for (int kt = 0; kt < 8; ++kt) {
      bf16x8 bfo = *(const bf16x8*)&wow[(wv * 16 + l15) * 264 + kt * 32 + lg * 8];
      bf16x8 bfg = *(const bf16x8*)&wow[(64 + wv * 16 + l15) * 264 + kt * 32 + lg * 8];
      po = MFMA(af[kt], bfo, po);
      pg = MFMA(af[kt], bfg, pg);
    }
    if (lane < 16) {
#pragma unroll
      for (int r = 0; r < 4; ++r)
        oacc[r] += (po[r] + tioR[r]) * fsig(pg[r]);
    }
  }
  // writeback state
  {
    f32x4 h4 = {hreg[0], hreg[1], hreg[2], hreg[3]};
    *(f32x4*)(hbuf + (size_t)(b0 + row) * 256 + wv * 64 + c4) = h4;
  }
  if (lane < 16) {
#pragma unroll
    for (int r = 0; r < 4; ++r) accb[(size_t)(b0 + r) * 64 + wv * 16 + lane] = oacc[r];
  }
}

__global__ void k4_out(const float* __restrict__ accb, float* __restrict__ out) {
  int i = blockIdx.x * 256 + threadIdx.x;
  out[i] = accb[i] * (1.0f / 512.0f);
}

extern "C" void kernel_launch(void* const* d_in, const int* in_sizes, int n_in,
                              void* d_out, int out_size, void* d_ws, size_t ws_size,
                              hipStream_t stream) {
  const float* x = (const float*)d_in[0];
  const float* h0 = (const float*)d_in[1];
  const float* Wih = (const float*)d_in[2];
  const float* bih = (const float*)d_in[3];
  const float* Whh = (const float*)d_in[4];
  const float* bhh = (const float*)d_in[5];
  const float* Wt = (const float*)d_in[6];
  const float* bt = (const float*)d_in[7];
  const float* Wo = (const float*)d_in[8];
  const float* bo = (const float*)d_in[9];
  const float* Wg = (const float*)d_in[10];
  const float* bg = (const float*)d_in[11];
  float* out = (float*)d_out;
  char* ws = (char*)d_ws;

  // pick largest power-of-2 time-chunk that fits ws
  int TC = 512;
  while (TC > 1 && (2035712ull + (size_t)TC * 1703936ull) > ws_size) TC >>= 1;
  int tcbits = 0;
  while ((1 << tcbits) != TC) ++tcbits;

  __bf16* win = (__bf16*)(ws + O_WIN);
  __bf16* whhb = (__bf16*)(ws + O_WHH);
  __bf16* wob = (__bf16*)(ws + O_WO);
  __bf16* wgb = (__bf16*)(ws + O_WG);
  float* b1 = (float*)(ws + O_B1);
  float* hbuf = (float*)(ws + O_H);
  float* accb = (float*)(ws + O_ACC);
  __bf16* tioc = (__bf16*)(ws + O_TIO);
  __bf16* xic = (__bf16*)(ws + O_TIO + (size_t)TC * 131072u);

  (void)hipFuncSetAttribute((const void*)k2_xi, hipFuncAttributeMaxDynamicSharedMemorySize, 69632);
  (void)hipFuncSetAttribute((const void*)k2_tio, hipFuncAttributeMaxDynamicSharedMemorySize, 137216);
  (void)hipFuncSetAttribute((const void*)k3_rec, hipFuncAttributeMaxDynamicSharedMemorySize, 110848);

  k1_prep<<<2692, 256, 0, stream>>>(Wih, Wt, Whh, Wo, Wg, bih, bhh, bt, h0, ws);
  int nch = 512 / TC;
  for (int c = 0; c < nch; ++c) {
    int t0 = c * TC;
    k2_xi<<<8 * TC, 256, 69632, stream>>>(x, win, b1, xic, t0, tcbits);
    k2_tio<<<8 * TC, 256, 137216, stream>>>(x, win, wob, b1, bo, tioc, t0, tcbits);
    k3_rec<<<256, 256, 110848, stream>>>(xic, tioc, whhb, wob, wgb, bhh + 512, bg, hbuf, accb, TC);
  }
  k4_out<<<256, 256, 0, stream>>>(accb, out);
}